// Round 23
// baseline (81.430 us; speedup 1.0000x reference)
//
#include <hip/hip_runtime.h>
#include <hip/hip_bf16.h>

#define M_ROWS 256
#define T_LEN  1024
#define NLAG   2048
#define CPYB   656    // bytes per copy slot = 16*41 (16B-aligned bases); 164 words == 4 mod 32
#define CPCH   39     // 16B chunks of data per copy (39*16 = 624)
#define NCOPY4 32
#define GPZW4  260    // u32 words per padded fp4 row (128 data | 128 zero | 4 wrap)

typedef __attribute__((ext_vector_type(4)))  unsigned int u32x4;
typedef __attribute__((ext_vector_type(8)))  int          i32x8;
typedef __attribute__((ext_vector_type(16))) float        f32x16;

// monotone f32 -> u32 map (order-preserving; no NaNs in this data)
static __device__ __forceinline__ unsigned int fmap(float f) {
  unsigned int b = __builtin_bit_cast(unsigned int, f);
  return (b & 0x80000000u) ? ~b : (b | 0x80000000u);
}
static __device__ __forceinline__ float funmap(unsigned int u) {
  return (u & 0x80000000u) ? __builtin_bit_cast(float, u & 0x7FFFFFFFu)
                           : __builtin_bit_cast(float, ~u);
}

// nearest fp4 e2m1 level: {0,.5,1,1.5,2,3,4,6}, midpoint thresholds
static __device__ __forceinline__ unsigned int fp4enc(float c) {
  float a = fabsf(c);
  unsigned int code = (unsigned int)(a >= 0.25f) + (unsigned int)(a >= 0.75f) +
                      (unsigned int)(a >= 1.25f) + (unsigned int)(a >= 1.75f) +
                      (unsigned int)(a >= 2.5f)  + (unsigned int)(a >= 3.5f) +
                      (unsigned int)(a >= 5.0f);
  return code | ((__builtin_bit_cast(unsigned int, c) >> 28) & 8u);
}

// ---------------- prep: center rows, fp4-ify, std(ddof=1); zero part ----------------
// f1 -> packed fp4 fragments f1p4[[ks][l5][row][4w]]; f2 -> padded fp4 rows gpz4[256][260w]
__global__ __launch_bounds__(256) void prep_kernel(
    const float* __restrict__ zis, const float* __restrict__ zjs,
    unsigned int* __restrict__ f1p4, unsigned int* __restrict__ gpz4,
    float* __restrict__ s1, float* __restrict__ s2, float* __restrict__ out,
    unsigned int* __restrict__ partu) {
  int r = blockIdx.x;  // 0..511
  const float* src = (r < M_ROWS) ? (zis + r * T_LEN) : (zjs + (r - M_ROWS) * T_LEN);
  int t = threadIdx.x;
  if (r == 0 && t == 0) out[0] = 0.0f;
  if (r < 256) partu[r * 256 + t] = 0u;   // atomicMax identity (maps below any real value)
  float4 v = reinterpret_cast<const float4*>(src)[t];
  float ls = v.x + v.y + v.z + v.w;
  for (int m = 1; m <= 32; m <<= 1) ls += __shfl_xor(ls, m, 64);
  __shared__ float red[4];
  __shared__ float red2[4];
  if ((t & 63) == 0) red[t >> 6] = ls;
  __syncthreads();
  float mean = (red[0] + red[1] + red[2] + red[3]) * (1.0f / 1024.0f);
  float c0 = v.x - mean, c1 = v.y - mean, c2 = v.z - mean, c3 = v.w - mean;
  float ss = c0 * c0 + c1 * c1 + c2 * c2 + c3 * c3;
  for (int m = 1; m <= 32; m <<= 1) ss += __shfl_xor(ss, m, 64);
  if ((t & 63) == 0) red2[t >> 6] = ss;
  __syncthreads();
  float sd = sqrtf((red2[0] + red2[1] + red2[2] + red2[3]) * (1.0f / 1023.0f));

  unsigned int h16 = fp4enc(c0) | (fp4enc(c1) << 4) | (fp4enc(c2) << 8) | (fp4enc(c3) << 12);
  unsigned int other = (unsigned int)__shfl_xor((int)h16, 1, 64);
  unsigned int word = h16 | (other << 16);   // valid on even t: elems 8*(t/2)..+7

  if (r < M_ROWS) {
    if (t == 0) s1[r] = sd;
    if (!(t & 1)) {
      int ks = t >> 4, l5 = (t >> 3) & 1, w = (t & 7) >> 1;
      f1p4[((ks * 2 + l5) * 256 + r) * 4 + w] = word;
    }
  } else {
    int j = r - M_ROWS;
    if (t == 0) s2[j] = sd;
    if (!(t & 1)) gpz4[j * GPZW4 + (t >> 1)] = word;       // data words 0..127
    if (t >= 128) gpz4[j * GPZW4 + t] = 0u;                // zero words 128..255
    if (!(t & 1) && (t >> 1) < 4) gpz4[j * GPZW4 + 256 + (t >> 1)] = word;  // wrap tail
  }
}

// ---- fully-unrolled phase with rolling G-window (8 names, prefetch distance 2) ----
// byte of quad Q = PBASE + 16*Q off per-lane base; step S uses quads 2S..2S+3
// (frag lf = quad 2S+3-lf, name W[q&7]); only 2 new quads per step.
// Epilogue: barrier-free atomicMax into part[j][row] (u32 monotone map).
template <int BP, int PC>
__device__ __forceinline__ void run_and_store(
    const unsigned char* __restrict__ ldsB, int gb_lane,
    const unsigned int* __restrict__ fbase,
    unsigned int* __restrict__ partu,
    int j, int rw, int l5, int l31) {
  constexpr int KA = PC ? 0 : 2 * BP;
  constexpr int N  = (PC ? (2 * BP + 2) : 16) - KA;   // even, >= 2
  constexpr int PBASE = PC ? (512 - 64 * BP) : 0;

  const unsigned char* gB = ldsB + gb_lane;   // per-lane VGPR base; rest immediate
  const unsigned int* fp = fbase + KA * 2048;

  f32x16 z00, z01, z02, z03, z10, z11, z12, z13;
#pragma unroll
  for (int q = 0; q < 16; ++q) {
    z00[q] = 0.f; z01[q] = 0.f; z02[q] = 0.f; z03[q] = 0.f;
    z10[q] = 0.f; z11[q] = 0.f; z12[q] = 0.f; z13[q] = 0.f;
  }

  i32x8 W0 = {0,0,0,0,0,0,0,0}, W1 = {0,0,0,0,0,0,0,0};
  i32x8 W2 = {0,0,0,0,0,0,0,0}, W3 = {0,0,0,0,0,0,0,0};
  i32x8 W4 = {0,0,0,0,0,0,0,0}, W5 = {0,0,0,0,0,0,0,0};
  i32x8 W6 = {0,0,0,0,0,0,0,0}, W7 = {0,0,0,0,0,0,0,0};
  i32x8 Fx0 = {0,0,0,0,0,0,0,0}, Fx1 = {0,0,0,0,0,0,0,0};
  i32x8 Fy0 = {0,0,0,0,0,0,0,0}, Fy1 = {0,0,0,0,0,0,0,0};

#define QLOAD(W, Q) { ((u32x4*)&(W))[0] = *(const u32x4*)(gB + PBASE + 16 * (Q)); }
#define FLOAD(F0, F1, S) {                                        \
    ((u32x4*)&(F0))[0] = *(const u32x4*)(fp + (S) * 2048);        \
    ((u32x4*)&(F1))[0] = *(const u32x4*)(fp + (S) * 2048 + 128); }
#define MFMA8(GA, GB, GC, GD, F0, F1) {                                                       \
    z00 = __builtin_amdgcn_mfma_scale_f32_32x32x64_f8f6f4(GA, F0, z00, 4, 4, 0, 127, 0, 127); \
    z10 = __builtin_amdgcn_mfma_scale_f32_32x32x64_f8f6f4(GA, F1, z10, 4, 4, 0, 127, 0, 127); \
    z01 = __builtin_amdgcn_mfma_scale_f32_32x32x64_f8f6f4(GB, F0, z01, 4, 4, 0, 127, 0, 127); \
    z11 = __builtin_amdgcn_mfma_scale_f32_32x32x64_f8f6f4(GB, F1, z11, 4, 4, 0, 127, 0, 127); \
    z02 = __builtin_amdgcn_mfma_scale_f32_32x32x64_f8f6f4(GC, F0, z02, 4, 4, 0, 127, 0, 127); \
    z12 = __builtin_amdgcn_mfma_scale_f32_32x32x64_f8f6f4(GC, F1, z12, 4, 4, 0, 127, 0, 127); \
    z03 = __builtin_amdgcn_mfma_scale_f32_32x32x64_f8f6f4(GD, F0, z03, 4, 4, 0, 127, 0, 127); \
    z13 = __builtin_amdgcn_mfma_scale_f32_32x32x64_f8f6f4(GD, F1, z13, 4, 4, 0, 127, 0, 127); }

  // prologue: quads 0..5 (steps 0 and 1), F for step 0
  QLOAD(W0, 0); QLOAD(W1, 1); QLOAD(W2, 2); QLOAD(W3, 3); QLOAD(W4, 4); QLOAD(W5, 5);
  FLOAD(Fx0, Fx1, 0);

  // period-4 step pattern; tail over-prefetches stay in defined LDS/workspace (unused)
#pragma unroll
  for (int s4 = 0; s4 < N / 4; ++s4) {
    const int S0 = 4 * s4;
    FLOAD(Fy0, Fy1, S0 + 1); QLOAD(W6, 2 * S0 + 6);  QLOAD(W7, 2 * S0 + 7);
    MFMA8(W3, W2, W1, W0, Fx0, Fx1);
    FLOAD(Fx0, Fx1, S0 + 2); QLOAD(W0, 2 * S0 + 8);  QLOAD(W1, 2 * S0 + 9);
    MFMA8(W5, W4, W3, W2, Fy0, Fy1);
    FLOAD(Fy0, Fy1, S0 + 3); QLOAD(W2, 2 * S0 + 10); QLOAD(W3, 2 * S0 + 11);
    MFMA8(W7, W6, W5, W4, Fx0, Fx1);
    FLOAD(Fx0, Fx1, S0 + 4); QLOAD(W4, 2 * S0 + 12); QLOAD(W5, 2 * S0 + 13);
    MFMA8(W1, W0, W7, W6, Fy0, Fy1);
  }
  if constexpr (N % 4 == 2) {
    constexpr int S0 = (N / 4) * 4;
    FLOAD(Fy0, Fy1, S0 + 1); QLOAD(W6, 2 * S0 + 6); QLOAD(W7, 2 * S0 + 7);
    MFMA8(W3, W2, W1, W0, Fx0, Fx1);
    FLOAD(Fx0, Fx1, S0 + 2); QLOAD(W0, 2 * S0 + 8); QLOAD(W1, 2 * S0 + 9);
    MFMA8(W5, W4, W3, W2, Fy0, Fy1);
  }

#undef QLOAD
#undef FLOAD
#undef MFMA8

  // ---- per-row max: lags lane-local -> fold + 1 shuffle -> barrier-free atomicMax ----
  float a0 = fmaxf(fmaxf(z00[0], z01[0]), fmaxf(z02[0], z03[0]));
  float a1 = fmaxf(fmaxf(z10[0], z11[0]), fmaxf(z12[0], z13[0]));
#pragma unroll
  for (int q = 1; q < 16; ++q) {
    a0 = fmaxf(a0, fmaxf(fmaxf(z00[q], z01[q]), fmaxf(z02[q], z03[q])));
    a1 = fmaxf(a1, fmaxf(fmaxf(z10[q], z11[q]), fmaxf(z12[q], z13[q])));
  }
  a0 = fmaxf(a0, __shfl_xor(a0, 32, 64));
  a1 = fmaxf(a1, __shfl_xor(a1, 32, 64));
  if (l5 == 0) {
    atomicMax(&partu[j * 256 + rw * 64 + l31], fmap(a0));       // rows rw*64 + 0..31
    atomicMax(&partu[j * 256 + rw * 64 + 32 + l31], fmap(a1));  // rows rw*64 + 32..63
  }
}

template <int BP>
__device__ __forceinline__ void do_pair(
    const unsigned char* __restrict__ ldsB, int gb_lane,
    const unsigned int* __restrict__ fbase,
    unsigned int* __restrict__ partu, int j, int rw, int l5, int l31) {
  run_and_store<BP, 0>(ldsB, gb_lane, fbase, partu, j, rw, l5, l31);
  run_and_store<BP, 1>(ldsB, gb_lane, fbase, partu, j, rw, l5, l31);
}

// ---------------- Toeplitz-GEMM correlation (MX-fp4, 2 bp-pairs per wg) ---------------
// grid: wg = h*256 + j ; 1024 wgs (2 generations), 256 threads = 4 waves.
// wg handles bp = 2h and 2h+1 (each paired with bp+8): 2 x 18 = 36 uniform k64-steps;
// shift-table built ONCE per wg. Barrier-free epilogue keeps waves decoupled throughout.
__global__ __launch_bounds__(256, 2) void corr_kernel(
    const unsigned int* __restrict__ f1p4,
    const unsigned int* __restrict__ gpz4,
    unsigned int* __restrict__ partu) {
  __shared__ __align__(16) unsigned char ldsB[NCOPY4 * CPYB];   // 20992 B

  int wg = blockIdx.x;
  int j = wg & 255;
  int h = wg >> 8;          // 0..3 -> bp = 2h, 2h+1

  int tid = threadIdx.x;
  int lane = tid & 63;
  int rw = tid >> 6;        // wave id = row quarter
  int l5 = lane >> 5;
  int l31 = lane & 31;

  // ---- build 32 range-compressed fp4 copies: 1248 16B chunks (once per wg) ----
  {
    const unsigned int* gj = gpz4 + j * GPZW4;
#pragma unroll
    for (int m = 0; m < 5; ++m) {
      int ch = m * 256 + tid;
      if (ch < NCOPY4 * CPCH) {
        int cp = ch / CPCH;           // magic-mul
        int cc = ch - cp * CPCH;
        int s = 32 * cc - 96 - cp;    // source elem of chunk start: x0 - cp
        int m0 = s + ((s < 0) ? 2048 : 0);
        int wb = m0 >> 3;
        int sh = (m0 & 7) << 2;
        unsigned int w0 = gj[wb], w1 = gj[wb + 1], w2 = gj[wb + 2],
                     w3 = gj[wb + 3], w4 = gj[wb + 4];
        u32x4 o;
        if (sh) {
          o[0] = (w0 >> sh) | (w1 << (32 - sh));
          o[1] = (w1 >> sh) | (w2 << (32 - sh));
          o[2] = (w2 >> sh) | (w3 << (32 - sh));
          o[3] = (w3 >> sh) | (w4 << (32 - sh));
        } else {
          o[0] = w0; o[1] = w1; o[2] = w2; o[3] = w3;
        }
        *reinterpret_cast<u32x4*>(ldsB + cp * CPYB + cc * 16) = o;
      }
    }
  }
  __syncthreads();

  // F (rows, MFMA-B): word idx ((ks*2+l5)*256 + row)*4
  const unsigned int* fbase = f1p4 + l5 * 1024 + ((rw * 64 + l31) << 2);
  int gb_lane = l31 * CPYB + 16 * l5;   // per-lane G base (everything else immediate)

  switch (h) {
    case 0: do_pair<0>(ldsB, gb_lane, fbase, partu, j, rw, l5, l31);
            do_pair<1>(ldsB, gb_lane, fbase, partu, j, rw, l5, l31); break;
    case 1: do_pair<2>(ldsB, gb_lane, fbase, partu, j, rw, l5, l31);
            do_pair<3>(ldsB, gb_lane, fbase, partu, j, rw, l5, l31); break;
    case 2: do_pair<4>(ldsB, gb_lane, fbase, partu, j, rw, l5, l31);
            do_pair<5>(ldsB, gb_lane, fbase, partu, j, rw, l5, l31); break;
    default: do_pair<6>(ldsB, gb_lane, fbase, partu, j, rw, l5, l31);
             do_pair<7>(ldsB, gb_lane, fbase, partu, j, rw, l5, l31); break;
  }
}

// ---------------- per-row CE: dist, logsumexp, pick target; atomic sum ----------------
__global__ __launch_bounds__(256) void loss_kernel(
    const unsigned int* __restrict__ partu, const float* __restrict__ s1,
    const float* __restrict__ s2, const int* __restrict__ speeds,
    float* __restrict__ out) {
  int i = blockIdx.x;
  int jt = threadIdx.x;
  float m = funmap(partu[jt * 256 + i]);
  float p = s1[i] * s2[jt];
  p = (p == 0.0f) ? 1.0f : p;
  float d = m / (p * 1023.0f);

  float t = d;
  for (int mk = 1; mk <= 32; mk <<= 1) t = fmaxf(t, __shfl_xor(t, mk, 64));
  __shared__ float wmax[4], wsum[4], sel;
  if ((jt & 63) == 0) wmax[jt >> 6] = t;
  if (jt == speeds[i]) sel = d;
  __syncthreads();
  float rmax = fmaxf(fmaxf(wmax[0], wmax[1]), fmaxf(wmax[2], wmax[3]));
  float e = expf(d - rmax);
  for (int mk = 1; mk <= 32; mk <<= 1) e += __shfl_xor(e, mk, 64);
  if ((jt & 63) == 0) wsum[jt >> 6] = e;
  __syncthreads();
  if (jt == 0) {
    float sum = wsum[0] + wsum[1] + wsum[2] + wsum[3];
    atomicAdd(out, rmax + logf(sum) - sel);
  }
}

extern "C" void kernel_launch(void* const* d_in, const int* in_sizes, int n_in,
                              void* d_out, int out_size, void* d_ws, size_t ws_size,
                              hipStream_t stream) {
  (void)in_sizes; (void)n_in; (void)out_size; (void)ws_size;
  const float* zis = (const float*)d_in[0];
  const float* zjs = (const float*)d_in[1];
  const int* speeds = (const int*)d_in[2];
  float* out = (float*)d_out;

  char* ws = (char*)d_ws;
  unsigned int* f1p4 = (unsigned int*)ws;                          // 128 KB packed fp4 A
  unsigned int* gpz4 = (unsigned int*)(ws + 131072);               // 260 KB padded fp4 rows
  float* s1 = (float*)(ws + 397312);                               // 1 KB
  float* s2 = (float*)(ws + 398336);                               // 1 KB
  unsigned int* partu = (unsigned int*)(ws + 399360);              // 256 KB u32 [j][row]

  prep_kernel<<<512, 256, 0, stream>>>(zis, zjs, f1p4, gpz4, s1, s2, out, partu);
  corr_kernel<<<1024, 256, 0, stream>>>(f1p4, gpz4, partu);
  loss_kernel<<<256, 256, 0, stream>>>(partu, s1, s2, speeds, out);
}

// Round 24
// 48.615 us; speedup vs baseline: 1.6750x; 1.6750x over previous
//
#include <hip/hip_runtime.h>
#include <hip/hip_bf16.h>

#define M_ROWS 256
#define T_LEN  1024
#define NLAG   2048
#define CPYB   656    // bytes per copy slot = 16*41 (16B-aligned bases); 164 words == 4 mod 32
#define CPCH   39     // 16B chunks of data per copy (39*16 = 624)
#define NCOPY4 32
#define GPZW4  260    // u32 words per padded fp4 row (128 data | 128 zero | 4 wrap)

typedef __attribute__((ext_vector_type(4)))  unsigned int u32x4;
typedef __attribute__((ext_vector_type(8)))  int          i32x8;
typedef __attribute__((ext_vector_type(16))) float        f32x16;

// monotone f32 -> u32 map (order-preserving; no NaNs in this data)
static __device__ __forceinline__ unsigned int fmap(float f) {
  unsigned int b = __builtin_bit_cast(unsigned int, f);
  return (b & 0x80000000u) ? ~b : (b | 0x80000000u);
}
static __device__ __forceinline__ float funmap(unsigned int u) {
  return (u & 0x80000000u) ? __builtin_bit_cast(float, u & 0x7FFFFFFFu)
                           : __builtin_bit_cast(float, ~u);
}

// nearest fp4 e2m1 level: {0,.5,1,1.5,2,3,4,6}, midpoint thresholds
static __device__ __forceinline__ unsigned int fp4enc(float c) {
  float a = fabsf(c);
  unsigned int code = (unsigned int)(a >= 0.25f) + (unsigned int)(a >= 0.75f) +
                      (unsigned int)(a >= 1.25f) + (unsigned int)(a >= 1.75f) +
                      (unsigned int)(a >= 2.5f)  + (unsigned int)(a >= 3.5f) +
                      (unsigned int)(a >= 5.0f);
  return code | ((__builtin_bit_cast(unsigned int, c) >> 28) & 8u);
}

// ---------------- prep: center rows, fp4-ify, std(ddof=1); zero part ----------------
// f1 -> packed fp4 fragments f1p4[[ks][l5][row][4w]]; f2 -> padded fp4 rows gpz4[256][260w]
__global__ __launch_bounds__(256) void prep_kernel(
    const float* __restrict__ zis, const float* __restrict__ zjs,
    unsigned int* __restrict__ f1p4, unsigned int* __restrict__ gpz4,
    float* __restrict__ s1, float* __restrict__ s2, float* __restrict__ out,
    unsigned int* __restrict__ partu) {
  int r = blockIdx.x;  // 0..511
  const float* src = (r < M_ROWS) ? (zis + r * T_LEN) : (zjs + (r - M_ROWS) * T_LEN);
  int t = threadIdx.x;
  if (r == 0 && t == 0) out[0] = 0.0f;
  if (r < 256) partu[r * 256 + t] = 0u;   // atomicMax identity (maps below any real value)
  float4 v = reinterpret_cast<const float4*>(src)[t];
  float ls = v.x + v.y + v.z + v.w;
  for (int m = 1; m <= 32; m <<= 1) ls += __shfl_xor(ls, m, 64);
  __shared__ float red[4];
  __shared__ float red2[4];
  if ((t & 63) == 0) red[t >> 6] = ls;
  __syncthreads();
  float mean = (red[0] + red[1] + red[2] + red[3]) * (1.0f / 1024.0f);
  float c0 = v.x - mean, c1 = v.y - mean, c2 = v.z - mean, c3 = v.w - mean;
  float ss = c0 * c0 + c1 * c1 + c2 * c2 + c3 * c3;
  for (int m = 1; m <= 32; m <<= 1) ss += __shfl_xor(ss, m, 64);
  if ((t & 63) == 0) red2[t >> 6] = ss;
  __syncthreads();
  float sd = sqrtf((red2[0] + red2[1] + red2[2] + red2[3]) * (1.0f / 1023.0f));

  unsigned int h16 = fp4enc(c0) | (fp4enc(c1) << 4) | (fp4enc(c2) << 8) | (fp4enc(c3) << 12);
  unsigned int other = (unsigned int)__shfl_xor((int)h16, 1, 64);
  unsigned int word = h16 | (other << 16);   // valid on even t: elems 8*(t/2)..+7

  if (r < M_ROWS) {
    if (t == 0) s1[r] = sd;
    if (!(t & 1)) {
      int ks = t >> 4, l5 = (t >> 3) & 1, w = (t & 7) >> 1;
      f1p4[((ks * 2 + l5) * 256 + r) * 4 + w] = word;
    }
  } else {
    int j = r - M_ROWS;
    if (t == 0) s2[j] = sd;
    if (!(t & 1)) gpz4[j * GPZW4 + (t >> 1)] = word;       // data words 0..127
    if (t >= 128) gpz4[j * GPZW4 + t] = 0u;                // zero words 128..255
    if (!(t & 1) && (t >> 1) < 4) gpz4[j * GPZW4 + 256 + (t >> 1)] = word;  // wrap tail
  }
}

// ---- fully-unrolled phase with rolling G-window (8 names, prefetch distance 2) ----
// byte of quad Q = PBASE + 16*Q off per-lane base; step S uses quads 2S..2S+3
// (frag lf = quad 2S+3-lf, name W[q&7]); only 2 new quads per step.
// Epilogue: barrier-free atomicMax into part[j][row] (u32 monotone map).
template <int BP, int PC>
__device__ __forceinline__ void run_and_store(
    const unsigned char* __restrict__ ldsB, int gb_lane,
    const unsigned int* __restrict__ fbase,
    unsigned int* __restrict__ partu,
    int j, int rw, int l5, int l31) {
  constexpr int KA = PC ? 0 : 2 * BP;
  constexpr int N  = (PC ? (2 * BP + 2) : 16) - KA;   // even, >= 2
  constexpr int PBASE = PC ? (512 - 64 * BP) : 0;

  const unsigned char* gB = ldsB + gb_lane;   // per-lane VGPR base; rest immediate
  const unsigned int* fp = fbase + KA * 2048;

  f32x16 z00, z01, z02, z03, z10, z11, z12, z13;
#pragma unroll
  for (int q = 0; q < 16; ++q) {
    z00[q] = 0.f; z01[q] = 0.f; z02[q] = 0.f; z03[q] = 0.f;
    z10[q] = 0.f; z11[q] = 0.f; z12[q] = 0.f; z13[q] = 0.f;
  }

  i32x8 W0 = {0,0,0,0,0,0,0,0}, W1 = {0,0,0,0,0,0,0,0};
  i32x8 W2 = {0,0,0,0,0,0,0,0}, W3 = {0,0,0,0,0,0,0,0};
  i32x8 W4 = {0,0,0,0,0,0,0,0}, W5 = {0,0,0,0,0,0,0,0};
  i32x8 W6 = {0,0,0,0,0,0,0,0}, W7 = {0,0,0,0,0,0,0,0};
  i32x8 Fx0 = {0,0,0,0,0,0,0,0}, Fx1 = {0,0,0,0,0,0,0,0};
  i32x8 Fy0 = {0,0,0,0,0,0,0,0}, Fy1 = {0,0,0,0,0,0,0,0};

#define QLOAD(W, Q) { ((u32x4*)&(W))[0] = *(const u32x4*)(gB + PBASE + 16 * (Q)); }
#define FLOAD(F0, F1, S) {                                        \
    ((u32x4*)&(F0))[0] = *(const u32x4*)(fp + (S) * 2048);        \
    ((u32x4*)&(F1))[0] = *(const u32x4*)(fp + (S) * 2048 + 128); }
#define MFMA8(GA, GB, GC, GD, F0, F1) {                                                       \
    z00 = __builtin_amdgcn_mfma_scale_f32_32x32x64_f8f6f4(GA, F0, z00, 4, 4, 0, 127, 0, 127); \
    z10 = __builtin_amdgcn_mfma_scale_f32_32x32x64_f8f6f4(GA, F1, z10, 4, 4, 0, 127, 0, 127); \
    z01 = __builtin_amdgcn_mfma_scale_f32_32x32x64_f8f6f4(GB, F0, z01, 4, 4, 0, 127, 0, 127); \
    z11 = __builtin_amdgcn_mfma_scale_f32_32x32x64_f8f6f4(GB, F1, z11, 4, 4, 0, 127, 0, 127); \
    z02 = __builtin_amdgcn_mfma_scale_f32_32x32x64_f8f6f4(GC, F0, z02, 4, 4, 0, 127, 0, 127); \
    z12 = __builtin_amdgcn_mfma_scale_f32_32x32x64_f8f6f4(GC, F1, z12, 4, 4, 0, 127, 0, 127); \
    z03 = __builtin_amdgcn_mfma_scale_f32_32x32x64_f8f6f4(GD, F0, z03, 4, 4, 0, 127, 0, 127); \
    z13 = __builtin_amdgcn_mfma_scale_f32_32x32x64_f8f6f4(GD, F1, z13, 4, 4, 0, 127, 0, 127); }

  // prologue: quads 0..5 (steps 0 and 1), F for step 0
  QLOAD(W0, 0); QLOAD(W1, 1); QLOAD(W2, 2); QLOAD(W3, 3); QLOAD(W4, 4); QLOAD(W5, 5);
  FLOAD(Fx0, Fx1, 0);

  // period-4 step pattern; tail over-prefetches stay in defined LDS/workspace (unused)
#pragma unroll
  for (int s4 = 0; s4 < N / 4; ++s4) {
    const int S0 = 4 * s4;
    FLOAD(Fy0, Fy1, S0 + 1); QLOAD(W6, 2 * S0 + 6);  QLOAD(W7, 2 * S0 + 7);
    MFMA8(W3, W2, W1, W0, Fx0, Fx1);
    FLOAD(Fx0, Fx1, S0 + 2); QLOAD(W0, 2 * S0 + 8);  QLOAD(W1, 2 * S0 + 9);
    MFMA8(W5, W4, W3, W2, Fy0, Fy1);
    FLOAD(Fy0, Fy1, S0 + 3); QLOAD(W2, 2 * S0 + 10); QLOAD(W3, 2 * S0 + 11);
    MFMA8(W7, W6, W5, W4, Fx0, Fx1);
    FLOAD(Fx0, Fx1, S0 + 4); QLOAD(W4, 2 * S0 + 12); QLOAD(W5, 2 * S0 + 13);
    MFMA8(W1, W0, W7, W6, Fy0, Fy1);
  }
  if constexpr (N % 4 == 2) {
    constexpr int S0 = (N / 4) * 4;
    FLOAD(Fy0, Fy1, S0 + 1); QLOAD(W6, 2 * S0 + 6); QLOAD(W7, 2 * S0 + 7);
    MFMA8(W3, W2, W1, W0, Fx0, Fx1);
    FLOAD(Fx0, Fx1, S0 + 2); QLOAD(W0, 2 * S0 + 8); QLOAD(W1, 2 * S0 + 9);
    MFMA8(W5, W4, W3, W2, Fy0, Fy1);
  }

#undef QLOAD
#undef FLOAD
#undef MFMA8

  // ---- per-row max: lags lane-local -> fold + 1 shuffle -> barrier-free atomicMax ----
  float a0 = fmaxf(fmaxf(z00[0], z01[0]), fmaxf(z02[0], z03[0]));
  float a1 = fmaxf(fmaxf(z10[0], z11[0]), fmaxf(z12[0], z13[0]));
#pragma unroll
  for (int q = 1; q < 16; ++q) {
    a0 = fmaxf(a0, fmaxf(fmaxf(z00[q], z01[q]), fmaxf(z02[q], z03[q])));
    a1 = fmaxf(a1, fmaxf(fmaxf(z10[q], z11[q]), fmaxf(z12[q], z13[q])));
  }
  a0 = fmaxf(a0, __shfl_xor(a0, 32, 64));
  a1 = fmaxf(a1, __shfl_xor(a1, 32, 64));
  if (l5 == 0) {
    atomicMax(&partu[j * 256 + rw * 64 + l31], fmap(a0));       // rows rw*64 + 0..31
    atomicMax(&partu[j * 256 + rw * 64 + 32 + l31], fmap(a1));  // rows rw*64 + 32..63
  }
}

template <int BP>
__device__ __forceinline__ void do_pair(
    const unsigned char* __restrict__ ldsB, int gb_lane,
    const unsigned int* __restrict__ fbase,
    unsigned int* __restrict__ partu, int j, int rw, int l5, int l31) {
  run_and_store<BP, 0>(ldsB, gb_lane, fbase, partu, j, rw, l5, l31);
  run_and_store<BP, 1>(ldsB, gb_lane, fbase, partu, j, rw, l5, l31);
}

// ---------------- Toeplitz-GEMM correlation (MX-fp4, barrier-free epilogue) ----------
// grid: wg = bp*256 + j ; 2048 wgs, 256 threads = 4 waves (wave rw = row quarter).
// wg does blk pair (bp, bp+8): 18 k64-steps, uniform. Wave tile 64 rows x 128 lags.
// After the build barrier the 4 waves are fully independent (no red, no epilogue barriers).
__global__ __launch_bounds__(256, 2) void corr_kernel(
    const unsigned int* __restrict__ f1p4,
    const unsigned int* __restrict__ gpz4,
    unsigned int* __restrict__ partu) {
  __shared__ __align__(16) unsigned char ldsB[NCOPY4 * CPYB];   // 20992 B

  int wg = blockIdx.x;
  int j = wg & 255;
  int bp = wg >> 8;         // 0..7

  int tid = threadIdx.x;
  int lane = tid & 63;
  int rw = tid >> 6;        // wave id = row quarter
  int l5 = lane >> 5;
  int l31 = lane & 31;

  // ---- build 32 range-compressed fp4 copies: 1248 16B chunks ----
  {
    const unsigned int* gj = gpz4 + j * GPZW4;
#pragma unroll
    for (int m = 0; m < 5; ++m) {
      int ch = m * 256 + tid;
      if (ch < NCOPY4 * CPCH) {
        int cp = ch / CPCH;           // magic-mul
        int cc = ch - cp * CPCH;
        int s = 32 * cc - 96 - cp;    // source elem of chunk start: x0 - cp
        int m0 = s + ((s < 0) ? 2048 : 0);
        int wb = m0 >> 3;
        int sh = (m0 & 7) << 2;
        unsigned int w0 = gj[wb], w1 = gj[wb + 1], w2 = gj[wb + 2],
                     w3 = gj[wb + 3], w4 = gj[wb + 4];
        u32x4 o;
        if (sh) {
          o[0] = (w0 >> sh) | (w1 << (32 - sh));
          o[1] = (w1 >> sh) | (w2 << (32 - sh));
          o[2] = (w2 >> sh) | (w3 << (32 - sh));
          o[3] = (w3 >> sh) | (w4 << (32 - sh));
        } else {
          o[0] = w0; o[1] = w1; o[2] = w2; o[3] = w3;
        }
        *reinterpret_cast<u32x4*>(ldsB + cp * CPYB + cc * 16) = o;
      }
    }
  }
  __syncthreads();

  // F (rows, MFMA-B): word idx ((ks*2+l5)*256 + row)*4
  const unsigned int* fbase = f1p4 + l5 * 1024 + ((rw * 64 + l31) << 2);
  int gb_lane = l31 * CPYB + 16 * l5;   // per-lane G base (everything else immediate)

  switch (bp) {
    case 0: do_pair<0>(ldsB, gb_lane, fbase, partu, j, rw, l5, l31); break;
    case 1: do_pair<1>(ldsB, gb_lane, fbase, partu, j, rw, l5, l31); break;
    case 2: do_pair<2>(ldsB, gb_lane, fbase, partu, j, rw, l5, l31); break;
    case 3: do_pair<3>(ldsB, gb_lane, fbase, partu, j, rw, l5, l31); break;
    case 4: do_pair<4>(ldsB, gb_lane, fbase, partu, j, rw, l5, l31); break;
    case 5: do_pair<5>(ldsB, gb_lane, fbase, partu, j, rw, l5, l31); break;
    case 6: do_pair<6>(ldsB, gb_lane, fbase, partu, j, rw, l5, l31); break;
    default: do_pair<7>(ldsB, gb_lane, fbase, partu, j, rw, l5, l31); break;
  }
}

// ---------------- per-row CE: dist, logsumexp, pick target; atomic sum ----------------
__global__ __launch_bounds__(256) void loss_kernel(
    const unsigned int* __restrict__ partu, const float* __restrict__ s1,
    const float* __restrict__ s2, const int* __restrict__ speeds,
    float* __restrict__ out) {
  int i = blockIdx.x;
  int jt = threadIdx.x;
  float m = funmap(partu[jt * 256 + i]);
  float p = s1[i] * s2[jt];
  p = (p == 0.0f) ? 1.0f : p;
  float d = m / (p * 1023.0f);

  float t = d;
  for (int mk = 1; mk <= 32; mk <<= 1) t = fmaxf(t, __shfl_xor(t, mk, 64));
  __shared__ float wmax[4], wsum[4], sel;
  if ((jt & 63) == 0) wmax[jt >> 6] = t;
  if (jt == speeds[i]) sel = d;
  __syncthreads();
  float rmax = fmaxf(fmaxf(wmax[0], wmax[1]), fmaxf(wmax[2], wmax[3]));
  float e = expf(d - rmax);
  for (int mk = 1; mk <= 32; mk <<= 1) e += __shfl_xor(e, mk, 64);
  if ((jt & 63) == 0) wsum[jt >> 6] = e;
  __syncthreads();
  if (jt == 0) {
    float sum = wsum[0] + wsum[1] + wsum[2] + wsum[3];
    atomicAdd(out, rmax + logf(sum) - sel);
  }
}

extern "C" void kernel_launch(void* const* d_in, const int* in_sizes, int n_in,
                              void* d_out, int out_size, void* d_ws, size_t ws_size,
                              hipStream_t stream) {
  (void)in_sizes; (void)n_in; (void)out_size; (void)ws_size;
  const float* zis = (const float*)d_in[0];
  const float* zjs = (const float*)d_in[1];
  const int* speeds = (const int*)d_in[2];
  float* out = (float*)d_out;

  char* ws = (char*)d_ws;
  unsigned int* f1p4 = (unsigned int*)ws;                          // 128 KB packed fp4 A
  unsigned int* gpz4 = (unsigned int*)(ws + 131072);               // 260 KB padded fp4 rows
  float* s1 = (float*)(ws + 397312);                               // 1 KB
  float* s2 = (float*)(ws + 398336);                               // 1 KB
  unsigned int* partu = (unsigned int*)(ws + 399360);              // 256 KB u32 [j][row]

  prep_kernel<<<512, 256, 0, stream>>>(zis, zjs, f1p4, gpz4, s1, s2, out, partu);
  corr_kernel<<<2048, 256, 0, stream>>>(f1p4, gpz4, partu);
  loss_kernel<<<256, 256, 0, stream>>>(partu, s1, s2, speeds, out);
}